// Round 1
// baseline (743.012 us; speedup 1.0000x reference)
//
#include <hip/hip_runtime.h>

#define NELEM 500000
#define NDOF 500000
#define HID 64

typedef _Float16 half2v __attribute__((ext_vector_type(2)));
typedef _Float16 half8v __attribute__((ext_vector_type(8)));
typedef float float4v __attribute__((ext_vector_type(4)));

__device__ __forceinline__ half2v pk(float a, float b) {
    return __builtin_bit_cast(half2v, __builtin_amdgcn_cvt_pkrtz(a, b));
}
__device__ __forceinline__ float fast_tanh(float x) {
    float cx = __builtin_amdgcn_fmed3f(x, -15.0f, 15.0f);
    float e = __expf(2.0f * cx);
    float r = __builtin_amdgcn_rcpf(e + 1.0f);
    return fmaf(-2.0f, r, 1.0f);
}
__device__ __forceinline__ float fdot2(half2v a, half2v b, float c) {
    return __builtin_amdgcn_fdot2(a, b, c, false);
}

// ds_swizzle BitMode (offset bit15=0): src_lane = ((lane & AND) | OR) ^ XOR,
// confined to 32-lane groups. offset = (XOR<<10) | (OR<<5) | AND.
//   quad broadcast j : AND=0x1C, OR=j   -> 0x1C,0x3C,0x5C,0x7C
//   xor 1 / xor 2    : 0x041F / 0x081F ; xor 4/8: 0x101F/0x201F
#define SWZF(x, pat) __builtin_bit_cast(float, \
    __builtin_amdgcn_ds_swizzle(__builtin_bit_cast(int, (x)), (pat)))

// GP-per-thread 3-phase: thread = one gauss point (64 elements x 4 GP per
// 256-thread block). B is loaded ONCE into registers and reused for the
// phase-3 B^T*sigma (no second 192MB stream). Element<->GP data exchange
// happens inside each 4-lane quad via ds_swizzle; LDS only carries the
// 4B/GP MLP activations and 8B/GP MLP outputs (3 KB total).
__global__ __launch_bounds__(256, 4) void fem_force_kernel(
    const float* __restrict__ u, const float* __restrict__ B,
    const float* __restrict__ Jacc, const float* __restrict__ gp_w,
    const int* __restrict__ conn, const float* __restrict__ weight1,
    const float* __restrict__ scales_inp, const float* __restrict__ limits_inp,
    const float* __restrict__ scales_grad, const float* __restrict__ limits_grad,
    const float* __restrict__ W1, const float* __restrict__ b1,
    const float* __restrict__ W2, const float* __restrict__ b2,
    const float* __restrict__ W3, const float* __restrict__ b3,
    float* __restrict__ F)
{
    __shared__ uint   sX[256];   // packed-f16 (x0,x1) per GP-row
    __shared__ float2 sG[256];   // MLP outputs per GP-row (row = tid)

    const int tid  = threadIdx.x;
    const int lane = tid & 63;
    const int wv   = tid >> 6;
    const int quad = lane >> 4;
    const int l15  = lane & 15;
    const int g    = tid & 3;            // gauss point of this thread
    const int e    = blockIdx.x * 64 + (tid >> 2);
    const bool valid = (e < NELEM);

    const float SQ23 = 0.816496580927726f;
    const float si0 = scales_inp[0], si1 = scales_inp[1];
    const float li0 = limits_inp[0], li1 = limits_inp[1];
    const float isg0 = 1.0f / scales_grad[0], isg1 = 1.0f / scales_grad[1];
    const float lg0 = limits_grad[0], lg1 = limits_grad[1];
    const float b30 = b3[0], b31 = b3[1];

    // ---- per-lane weight fragments (identical layouts to verified kernel) ----
    // Layer1: lane's 16 k's are f*32 + quad*8 + j (A-layout cols); b1 packed f16
    half2v w1p[16];
    half2v b1p[8];
#pragma unroll
    for (int f = 0; f < 2; f++)
#pragma unroll
        for (int jj = 0; jj < 4; jj++) {
            const int k0 = f * 32 + quad * 8 + 2 * jj;
            w1p[f * 8 + 2 * jj]     = pk(W1[k0],     W1[HID + k0]);
            w1p[f * 8 + 2 * jj + 1] = pk(W1[k0 + 1], W1[HID + k0 + 1]);
            b1p[f * 4 + jj] = pk(b1[k0], b1[k0 + 1]);
        }
    // Layer2 B-frags: B[k = f*32+quad*8+j][n = t*16+l15], f16 packed pairs
    half8v bf[4][2];
#pragma unroll
    for (int t = 0; t < 4; t++)
#pragma unroll
        for (int f = 0; f < 2; f++) {
            union { half8v v; uint uu[4]; } tmp;
#pragma unroll
            for (int jj = 0; jj < 4; jj++) {
                const int k0 = f * 32 + quad * 8 + 2 * jj;
                const int n  = t * 16 + l15;
                tmp.uu[jj] = __builtin_bit_cast(uint,
                    pk(W2[k0 * HID + n], W2[(k0 + 1) * HID + n]));
            }
            bf[t][f] = tmp.v;
        }
    float b2f[4], w3a[4], w3b[4];
#pragma unroll
    for (int t = 0; t < 4; t++) {
        const int n = t * 16 + l15;
        b2f[t] = b2[n];
        w3a[t] = W3[2 * n];
        w3b[t] = W3[2 * n + 1];
    }

    // ---- phase 1: strain invariants for this thread's GP ----
    float Bg[24];                       // this GP's B, kept live through phase 2
    float fw = 0.f, fd00 = 0.f, fd11 = 0.f, fd01 = 0.f;
    int nd = 0;                         // this thread's node id
    uint xw = 0u;
    if (valid) {
        const int4 c4 = ((const int4*)conn)[e];
        nd = (g == 0) ? c4.x : (g == 1) ? c4.y : (g == 2) ? c4.z : c4.w;
        // one 8B pair of u and weight1 per thread; quad shares via swizzle
        const float2 uu = *(const float2*)(u + 2 * nd);
        const float2 wv2 = *(const float2*)(weight1 + 2 * nd);
        const float vx = wv2.x * uu.x, vy = wv2.y * uu.y;
        float ue[8];
        ue[0] = SWZF(vx, 0x1C); ue[1] = SWZF(vy, 0x1C);
        ue[2] = SWZF(vx, 0x3C); ue[3] = SWZF(vy, 0x3C);
        ue[4] = SWZF(vx, 0x5C); ue[5] = SWZF(vy, 0x5C);
        ue[6] = SWZF(vx, 0x7C); ue[7] = SWZF(vy, 0x7C);

        // this GP's 96B of B -> registers (read once for the whole kernel)
        const float4* Bp = (const float4*)(B + (size_t)(e * 4 + g) * 24);
#pragma unroll
        for (int t2 = 0; t2 < 6; t2++) {
            const float4 v = Bp[t2];
            Bg[4 * t2 + 0] = v.x; Bg[4 * t2 + 1] = v.y;
            Bg[4 * t2 + 2] = v.z; Bg[4 * t2 + 3] = v.w;
        }
        float s0 = 0.f, s1 = 0.f, s2 = 0.f;
#pragma unroll
        for (int j = 0; j < 8; j++) {
            s0 = fmaf(Bg[j],      ue[j], s0);
            s1 = fmaf(Bg[8 + j],  ue[j], s1);
            s2 = fmaf(Bg[16 + j], ue[j], s2);
        }
        const float ev  = s0 + s1;
        const float ev3 = ev * (1.0f / 3.0f);
        const float d00 = s0 - ev3, d11 = s1 - ev3, d22 = -ev3, d01 = 0.5f * s2;
        const float det = sqrtf(d00 * d00 + d11 * d11 + d22 * d22 + 2.0f * d01 * d01);
        const float rd  = __builtin_amdgcn_rcpf(det);
        const float es  = det * SQ23;
        const float wgt = Jacc[4 * e + g] * gp_w[g];
        // fold for phase 3: f0 = p*wgt + q*fd00, f1 = p*wgt + q*fd11, f2 = q*fd01
        const float sc = SQ23 * rd * wgt;
        fw = wgt; fd00 = sc * d00; fd11 = sc * d11; fd01 = sc * d01;
        xw = __builtin_bit_cast(uint, pk(fmaf(ev, si0, li0), fmaf(es, si1, li1)));
    }
    sX[tid] = xw;                       // invalid lanes write zeros
    __syncthreads();

    // ---- phase 2: wave-level MFMA MLP over this wave's 64 GP-rows ----
#pragma unroll 1
    for (int rt = 0; rt < 4; rt++) {
        const int tb = wv * 64 + rt * 16;
        const half2v xp = __builtin_bit_cast(half2v, sX[tb + l15]);

        // layer 1 -> A-frags (row m = l15, cols per lane)
        union { half8v v; uint uu[4]; } A0, A1;
#pragma unroll
        for (int jj = 0; jj < 4; jj++) {
            const float t0 = fast_tanh(fdot2(xp, w1p[2 * jj],     (float)b1p[jj][0]));
            const float t1 = fast_tanh(fdot2(xp, w1p[2 * jj + 1], (float)b1p[jj][1]));
            const float t2 = fast_tanh(fdot2(xp, w1p[8 + 2 * jj],     (float)b1p[4 + jj][0]));
            const float t3 = fast_tanh(fdot2(xp, w1p[8 + 2 * jj + 1], (float)b1p[4 + jj][1]));
            A0.uu[jj] = __builtin_bit_cast(uint, pk(t0, t1));
            A1.uu[jj] = __builtin_bit_cast(uint, pk(t2, t3));
        }

        // layer 2 via MFMA + tanh + layer-3 partials
        float s0[4] = {0.f, 0.f, 0.f, 0.f};
        float s1[4] = {0.f, 0.f, 0.f, 0.f};
#pragma unroll
        for (int t = 0; t < 4; t++) {
            float4v c = {b2f[t], b2f[t], b2f[t], b2f[t]};
            c = __builtin_amdgcn_mfma_f32_16x16x32_f16(A0.v, bf[t][0], c, 0, 0, 0);
            c = __builtin_amdgcn_mfma_f32_16x16x32_f16(A1.v, bf[t][1], c, 0, 0, 0);
#pragma unroll
            for (int reg = 0; reg < 4; reg++) {
                const float h = fast_tanh(c[reg]);
                s0[reg] = fmaf(h, w3a[t], s0[reg]);
                s1[reg] = fmaf(h, w3b[t], s1[reg]);
            }
        }
        // reduce over the 16 col-lanes (xor masks < 16 stay in group)
#pragma unroll
        for (int reg = 0; reg < 4; reg++) { s0[reg] += SWZF(s0[reg], 0x041F); s1[reg] += SWZF(s1[reg], 0x041F); }
#pragma unroll
        for (int reg = 0; reg < 4; reg++) { s0[reg] += SWZF(s0[reg], 0x081F); s1[reg] += SWZF(s1[reg], 0x081F); }
#pragma unroll
        for (int reg = 0; reg < 4; reg++) { s0[reg] += SWZF(s0[reg], 0x101F); s1[reg] += SWZF(s1[reg], 0x101F); }
#pragma unroll
        for (int reg = 0; reg < 4; reg++) { s0[reg] += SWZF(s0[reg], 0x201F); s1[reg] += SWZF(s1[reg], 0x201F); }
        // writer lanes l15<4 emit row (quad*4 + l15) of this tile
        if (l15 < 4) {
            float a = s0[0], b = s1[0];
            if (l15 == 1) { a = s0[1]; b = s1[1]; }
            if (l15 == 2) { a = s0[2]; b = s1[2]; }
            if (l15 == 3) { a = s0[3]; b = s1[3]; }
            sG[tb + quad * 4 + l15] = make_float2(a, b);
        }
    }
    __syncthreads();

    // ---- phase 3: stress from registers -> quad-reduce -> 2 atomics ----
    if (valid) {
        const float2 gv = sG[tid];
        const float p = (gv.x + b30 - lg0) * isg0;
        const float q = (gv.y + b31 - lg1) * isg1;
        const float pw = p * fw;
        const float f0 = fmaf(q, fd00, pw);
        const float f1 = fmaf(q, fd11, pw);
        const float f2 = q * fd01;
        float EP[8];
#pragma unroll
        for (int j = 0; j < 8; j++)
            EP[j] = fmaf(Bg[j], f0, fmaf(Bg[8 + j], f1, Bg[16 + j] * f2));
        // sum the 4 gauss points of this element (quad xor-reduce)
#pragma unroll
        for (int j = 0; j < 8; j++) EP[j] += SWZF(EP[j], 0x041F);
#pragma unroll
        for (int j = 0; j < 8; j++) EP[j] += SWZF(EP[j], 0x081F);
        // thread g scatters its own node's dof pair
        float a = EP[0], b = EP[1];
        if (g == 1) { a = EP[2]; b = EP[3]; }
        if (g == 2) { a = EP[4]; b = EP[5]; }
        if (g == 3) { a = EP[6]; b = EP[7]; }
        atomicAdd(&F[2 * nd],     a);
        atomicAdd(&F[2 * nd + 1], b);
    }
}

extern "C" void kernel_launch(void* const* d_in, const int* in_sizes, int n_in,
                              void* d_out, int out_size, void* d_ws, size_t ws_size,
                              hipStream_t stream) {
    const float* u           = (const float*)d_in[0];
    const float* B           = (const float*)d_in[1];
    const float* Jacc        = (const float*)d_in[2];
    const float* gp_w        = (const float*)d_in[3];
    const int*   conn        = (const int*)  d_in[4];
    const float* weight1     = (const float*)d_in[5];
    const float* scales_inp  = (const float*)d_in[6];
    const float* limits_inp  = (const float*)d_in[7];
    const float* scales_grad = (const float*)d_in[8];
    const float* limits_grad = (const float*)d_in[9];
    const float* W1          = (const float*)d_in[10];
    const float* b1          = (const float*)d_in[11];
    const float* W2          = (const float*)d_in[12];
    const float* b2          = (const float*)d_in[13];
    const float* W3          = (const float*)d_in[14];
    const float* b3          = (const float*)d_in[15];
    float* F = (float*)d_out;

    (void)hipMemsetAsync(d_out, 0, sizeof(float) * NDOF, stream);

    const int grid = (NELEM + 63) / 64;   // 64 elements (256 GPs) per block
    fem_force_kernel<<<grid, 256, 0, stream>>>(
        u, B, Jacc, gp_w, conn, weight1, scales_inp, limits_inp,
        scales_grad, limits_grad, W1, b1, W2, b2, W3, b3, F);
}

// Round 2
// 464.750 us; speedup vs baseline: 1.5987x; 1.5987x over previous
//
#include <hip/hip_runtime.h>

#define NELEM 500000
#define NDOF 500000
#define HID 64

typedef _Float16 half2v __attribute__((ext_vector_type(2)));
typedef _Float16 half8v __attribute__((ext_vector_type(8)));
typedef float float4v __attribute__((ext_vector_type(4)));

__device__ __forceinline__ half2v pk(float a, float b) {
    return __builtin_bit_cast(half2v, __builtin_amdgcn_cvt_pkrtz(a, b));
}
__device__ __forceinline__ float fast_tanh(float x) {
    float cx = __builtin_amdgcn_fmed3f(x, -15.0f, 15.0f);
    float e = __expf(2.0f * cx);
    float r = __builtin_amdgcn_rcpf(e + 1.0f);
    return fmaf(-2.0f, r, 1.0f);
}
__device__ __forceinline__ float fdot2(half2v a, half2v b, float c) {
    return __builtin_amdgcn_fdot2(a, b, c, false);
}

// ds_swizzle BitMode (offset bit15=0): src_lane = ((lane & AND) | OR) ^ XOR,
// confined to 32-lane groups. offset = (XOR<<10) | (OR<<5) | AND.
//   quad broadcast j : AND=0x1C, OR=j   -> 0x1C,0x3C,0x5C,0x7C
//   xor 1 / xor 2    : 0x041F / 0x081F ; xor 4/8: 0x101F/0x201F
#define SWZF(x, pat) __builtin_bit_cast(float, \
    __builtin_amdgcn_ds_swizzle(__builtin_bit_cast(int, (x)), (pat)))

// GP-per-thread 3-phase: thread = one gauss point (64 elements x 4 GP per
// 256-thread block). B is loaded ONCE from HBM; to avoid holding 24 VGPRs
// live across the MFMA phase (round-1 spill disaster: 840MB scratch writes),
// B is stashed in LDS ([256][25] padded stride -> conflict-free) between
// phase 1 and phase 3. launch_bounds(256,2): 256-VGPR cap, proven spill-free.
__global__ __launch_bounds__(256, 2) void fem_force_kernel(
    const float* __restrict__ u, const float* __restrict__ B,
    const float* __restrict__ Jacc, const float* __restrict__ gp_w,
    const int* __restrict__ conn, const float* __restrict__ weight1,
    const float* __restrict__ scales_inp, const float* __restrict__ limits_inp,
    const float* __restrict__ scales_grad, const float* __restrict__ limits_grad,
    const float* __restrict__ W1, const float* __restrict__ b1,
    const float* __restrict__ W2, const float* __restrict__ b2,
    const float* __restrict__ W3, const float* __restrict__ b3,
    float* __restrict__ F)
{
    __shared__ uint   sX[256];       // packed-f16 (x0,x1) per GP-row
    __shared__ float2 sG[256];       // MLP outputs per GP-row (row = tid)
    __shared__ float  sB[256][25];   // per-thread B stash, pad->conflict-free

    const int tid  = threadIdx.x;
    const int lane = tid & 63;
    const int wv   = tid >> 6;
    const int quad = lane >> 4;
    const int l15  = lane & 15;
    const int g    = tid & 3;            // gauss point of this thread
    const int e    = blockIdx.x * 64 + (tid >> 2);
    const bool valid = (e < NELEM);

    const float SQ23 = 0.816496580927726f;
    const float si0 = scales_inp[0], si1 = scales_inp[1];
    const float li0 = limits_inp[0], li1 = limits_inp[1];
    const float isg0 = 1.0f / scales_grad[0], isg1 = 1.0f / scales_grad[1];
    const float lg0 = limits_grad[0], lg1 = limits_grad[1];
    const float b30 = b3[0], b31 = b3[1];

    // ---- per-lane weight fragments (layouts identical to verified kernel) ----
    // Layer1: lane's 16 k's are f*32 + quad*8 + j (A-layout cols); b1 packed f16
    half2v w1p[16];
    half2v b1p[8];
#pragma unroll
    for (int f = 0; f < 2; f++)
#pragma unroll
        for (int jj = 0; jj < 4; jj++) {
            const int k0 = f * 32 + quad * 8 + 2 * jj;
            w1p[f * 8 + 2 * jj]     = pk(W1[k0],     W1[HID + k0]);
            w1p[f * 8 + 2 * jj + 1] = pk(W1[k0 + 1], W1[HID + k0 + 1]);
            b1p[f * 4 + jj] = pk(b1[k0], b1[k0 + 1]);
        }
    // Layer2 B-frags: B[k = f*32+quad*8+j][n = t*16+l15], f16 packed pairs
    half8v bf[4][2];
#pragma unroll
    for (int t = 0; t < 4; t++)
#pragma unroll
        for (int f = 0; f < 2; f++) {
            union { half8v v; uint uu[4]; } tmp;
#pragma unroll
            for (int jj = 0; jj < 4; jj++) {
                const int k0 = f * 32 + quad * 8 + 2 * jj;
                const int n  = t * 16 + l15;
                tmp.uu[jj] = __builtin_bit_cast(uint,
                    pk(W2[k0 * HID + n], W2[(k0 + 1) * HID + n]));
            }
            bf[t][f] = tmp.v;
        }
    float b2f[4], w3a[4], w3b[4];
#pragma unroll
    for (int t = 0; t < 4; t++) {
        const int n = t * 16 + l15;
        b2f[t] = b2[n];
        w3a[t] = W3[2 * n];
        w3b[t] = W3[2 * n + 1];
    }

    // ---- phase 1: strain invariants for this thread's GP ----
    float fw = 0.f, fd00 = 0.f, fd11 = 0.f, fd01 = 0.f;
    int nd = 0;                         // this thread's node id
    uint xw = 0u;
    if (valid) {
        const int4 c4 = ((const int4*)conn)[e];
        nd = (g == 0) ? c4.x : (g == 1) ? c4.y : (g == 2) ? c4.z : c4.w;
        // one 8B pair of u and weight1 per thread; quad shares via swizzle
        const float2 uu = *(const float2*)(u + 2 * nd);
        const float2 wv2 = *(const float2*)(weight1 + 2 * nd);
        const float vx = wv2.x * uu.x, vy = wv2.y * uu.y;
        float ue[8];
        ue[0] = SWZF(vx, 0x1C); ue[1] = SWZF(vy, 0x1C);
        ue[2] = SWZF(vx, 0x3C); ue[3] = SWZF(vy, 0x3C);
        ue[4] = SWZF(vx, 0x5C); ue[5] = SWZF(vy, 0x5C);
        ue[6] = SWZF(vx, 0x7C); ue[7] = SWZF(vy, 0x7C);

        // this GP's 96B of B -> registers (strain) -> LDS stash (phase 3)
        float Bg[24];
        const float4* Bp = (const float4*)(B + (size_t)(e * 4 + g) * 24);
#pragma unroll
        for (int t2 = 0; t2 < 6; t2++) {
            const float4 v = Bp[t2];
            Bg[4 * t2 + 0] = v.x; Bg[4 * t2 + 1] = v.y;
            Bg[4 * t2 + 2] = v.z; Bg[4 * t2 + 3] = v.w;
        }
        float s0 = 0.f, s1 = 0.f, s2 = 0.f;
#pragma unroll
        for (int j = 0; j < 8; j++) {
            s0 = fmaf(Bg[j],      ue[j], s0);
            s1 = fmaf(Bg[8 + j],  ue[j], s1);
            s2 = fmaf(Bg[16 + j], ue[j], s2);
        }
#pragma unroll
        for (int j = 0; j < 24; j++) sB[tid][j] = Bg[j];   // free Bg's regs

        const float ev  = s0 + s1;
        const float ev3 = ev * (1.0f / 3.0f);
        const float d00 = s0 - ev3, d11 = s1 - ev3, d22 = -ev3, d01 = 0.5f * s2;
        const float det = sqrtf(d00 * d00 + d11 * d11 + d22 * d22 + 2.0f * d01 * d01);
        const float rd  = __builtin_amdgcn_rcpf(det);
        const float es  = det * SQ23;
        const float wgt = Jacc[4 * e + g] * gp_w[g];
        // fold for phase 3: f0 = p*wgt + q*fd00, f1 = p*wgt + q*fd11, f2 = q*fd01
        const float sc = SQ23 * rd * wgt;
        fw = wgt; fd00 = sc * d00; fd11 = sc * d11; fd01 = sc * d01;
        xw = __builtin_bit_cast(uint, pk(fmaf(ev, si0, li0), fmaf(es, si1, li1)));
    }
    sX[tid] = xw;                       // invalid lanes write zeros
    __syncthreads();

    // ---- phase 2: wave-level MFMA MLP over this wave's 64 GP-rows ----
#pragma unroll 1
    for (int rt = 0; rt < 4; rt++) {
        const int tb = wv * 64 + rt * 16;
        const half2v xp = __builtin_bit_cast(half2v, sX[tb + l15]);

        // layer 1 -> A-frags (row m = l15, cols per lane)
        union { half8v v; uint uu[4]; } A0, A1;
#pragma unroll
        for (int jj = 0; jj < 4; jj++) {
            const float t0 = fast_tanh(fdot2(xp, w1p[2 * jj],     (float)b1p[jj][0]));
            const float t1 = fast_tanh(fdot2(xp, w1p[2 * jj + 1], (float)b1p[jj][1]));
            const float t2 = fast_tanh(fdot2(xp, w1p[8 + 2 * jj],     (float)b1p[4 + jj][0]));
            const float t3 = fast_tanh(fdot2(xp, w1p[8 + 2 * jj + 1], (float)b1p[4 + jj][1]));
            A0.uu[jj] = __builtin_bit_cast(uint, pk(t0, t1));
            A1.uu[jj] = __builtin_bit_cast(uint, pk(t2, t3));
        }

        // layer 2 via MFMA + tanh + layer-3 partials
        float s0[4] = {0.f, 0.f, 0.f, 0.f};
        float s1[4] = {0.f, 0.f, 0.f, 0.f};
#pragma unroll
        for (int t = 0; t < 4; t++) {
            float4v c = {b2f[t], b2f[t], b2f[t], b2f[t]};
            c = __builtin_amdgcn_mfma_f32_16x16x32_f16(A0.v, bf[t][0], c, 0, 0, 0);
            c = __builtin_amdgcn_mfma_f32_16x16x32_f16(A1.v, bf[t][1], c, 0, 0, 0);
#pragma unroll
            for (int reg = 0; reg < 4; reg++) {
                const float h = fast_tanh(c[reg]);
                s0[reg] = fmaf(h, w3a[t], s0[reg]);
                s1[reg] = fmaf(h, w3b[t], s1[reg]);
            }
        }
        // reduce over the 16 col-lanes (xor masks < 16 stay in group)
#pragma unroll
        for (int reg = 0; reg < 4; reg++) { s0[reg] += SWZF(s0[reg], 0x041F); s1[reg] += SWZF(s1[reg], 0x041F); }
#pragma unroll
        for (int reg = 0; reg < 4; reg++) { s0[reg] += SWZF(s0[reg], 0x081F); s1[reg] += SWZF(s1[reg], 0x081F); }
#pragma unroll
        for (int reg = 0; reg < 4; reg++) { s0[reg] += SWZF(s0[reg], 0x101F); s1[reg] += SWZF(s1[reg], 0x101F); }
#pragma unroll
        for (int reg = 0; reg < 4; reg++) { s0[reg] += SWZF(s0[reg], 0x201F); s1[reg] += SWZF(s1[reg], 0x201F); }
        // writer lanes l15<4 emit row (quad*4 + l15) of this tile
        if (l15 < 4) {
            float a = s0[0], b = s1[0];
            if (l15 == 1) { a = s0[1]; b = s1[1]; }
            if (l15 == 2) { a = s0[2]; b = s1[2]; }
            if (l15 == 3) { a = s0[3]; b = s1[3]; }
            sG[tb + quad * 4 + l15] = make_float2(a, b);
        }
    }
    __syncthreads();

    // ---- phase 3: stress from LDS stash -> quad-reduce -> 2 atomics ----
    if (valid) {
        const float2 gv = sG[tid];
        const float p = (gv.x + b30 - lg0) * isg0;
        const float q = (gv.y + b31 - lg1) * isg1;
        const float pw = p * fw;
        const float f0 = fmaf(q, fd00, pw);
        const float f1 = fmaf(q, fd11, pw);
        const float f2 = q * fd01;
        float EP[8];
#pragma unroll
        for (int j = 0; j < 8; j++)
            EP[j] = fmaf(sB[tid][j], f0,
                    fmaf(sB[tid][8 + j], f1, sB[tid][16 + j] * f2));
        // sum the 4 gauss points of this element (quad xor-reduce)
#pragma unroll
        for (int j = 0; j < 8; j++) EP[j] += SWZF(EP[j], 0x041F);
#pragma unroll
        for (int j = 0; j < 8; j++) EP[j] += SWZF(EP[j], 0x081F);
        // thread g scatters its own node's dof pair
        float a = EP[0], b = EP[1];
        if (g == 1) { a = EP[2]; b = EP[3]; }
        if (g == 2) { a = EP[4]; b = EP[5]; }
        if (g == 3) { a = EP[6]; b = EP[7]; }
        atomicAdd(&F[2 * nd],     a);
        atomicAdd(&F[2 * nd + 1], b);
    }
}

extern "C" void kernel_launch(void* const* d_in, const int* in_sizes, int n_in,
                              void* d_out, int out_size, void* d_ws, size_t ws_size,
                              hipStream_t stream) {
    const float* u           = (const float*)d_in[0];
    const float* B           = (const float*)d_in[1];
    const float* Jacc        = (const float*)d_in[2];
    const float* gp_w        = (const float*)d_in[3];
    const int*   conn        = (const int*)  d_in[4];
    const float* weight1     = (const float*)d_in[5];
    const float* scales_inp  = (const float*)d_in[6];
    const float* limits_inp  = (const float*)d_in[7];
    const float* scales_grad = (const float*)d_in[8];
    const float* limits_grad = (const float*)d_in[9];
    const float* W1          = (const float*)d_in[10];
    const float* b1          = (const float*)d_in[11];
    const float* W2          = (const float*)d_in[12];
    const float* b2          = (const float*)d_in[13];
    const float* W3          = (const float*)d_in[14];
    const float* b3          = (const float*)d_in[15];
    float* F = (float*)d_out;

    (void)hipMemsetAsync(d_out, 0, sizeof(float) * NDOF, stream);

    const int grid = (NELEM + 63) / 64;   // 64 elements (256 GPs) per block
    fem_force_kernel<<<grid, 256, 0, stream>>>(
        u, B, Jacc, gp_w, conn, weight1, scales_inp, limits_inp,
        scales_grad, limits_grad, W1, b1, W2, b2, W3, b3, F);
}

// Round 3
// 461.789 us; speedup vs baseline: 1.6090x; 1.0064x over previous
//
#include <hip/hip_runtime.h>

#define NELEM 500000
#define NDOF 500000
#define HID 64

typedef _Float16 half2v __attribute__((ext_vector_type(2)));
typedef _Float16 half8v __attribute__((ext_vector_type(8)));
typedef float float4v __attribute__((ext_vector_type(4)));

// lambda = 2*log2(e): prescaled into W1,b1,W2,b2 so tanh needs no multiply.
#define LAM 2.885390081777927f

__device__ __forceinline__ half2v pk(float a, float b) {
    return __builtin_bit_cast(half2v, __builtin_amdgcn_cvt_pkrtz(a, b));
}
// tanh(z) where y = LAM*z is the prescaled input. exp2(+-inf) saturates
// correctly (inf -> t=1, 0 -> t=-1), so no clamp needed.
__device__ __forceinline__ float tanh2(float y) {
    float e = __builtin_amdgcn_exp2f(y);
    float r = __builtin_amdgcn_rcpf(e + 1.0f);
    return fmaf(-2.0f, r, 1.0f);
}
__device__ __forceinline__ float fdot2(half2v a, half2v b, float c) {
    return __builtin_amdgcn_fdot2(a, b, c, false);
}

// ds_swizzle BitMode: src_lane = ((lane & AND) | OR) ^ XOR within 32-lane
// groups. offset = (XOR<<10)|(OR<<5)|AND.
//   quad broadcast j: 0x1C,0x3C,0x5C,0x7C ; xor16: 0x401F
#define SWZF(x, pat) __builtin_bit_cast(float, \
    __builtin_amdgcn_ds_swizzle(__builtin_bit_cast(int, (x)), (pat)))

// GP-per-thread 3-phase, swapped-MFMA variant.
// Layer-2 computes z2^T = (LAM*W2^T) @ H1^T so the MLP output lands with
// GP-row on l15 and hidden on quad*4+reg: the layer-3 reduction is over
// QUADS (2 cross-lane steps x 2 values) instead of 16 lanes (4 steps x 8).
// Phase 3 is folded to EP[j] = p*P[j] + q*Q[j] with P,Q stashed in LDS by
// phase 1 (16 floats/GP); weight regs (112) are loaded AFTER phase 1 so
// they never overlap Bg[24] (round-1 spill lesson).
__global__ __launch_bounds__(256, 3) void fem_force_kernel(
    const float* __restrict__ u, const float* __restrict__ B,
    const float* __restrict__ Jacc, const float* __restrict__ gp_w,
    const int* __restrict__ conn, const float* __restrict__ weight1,
    const float* __restrict__ scales_inp, const float* __restrict__ limits_inp,
    const float* __restrict__ scales_grad, const float* __restrict__ limits_grad,
    const float* __restrict__ W1, const float* __restrict__ b1,
    const float* __restrict__ W2, const float* __restrict__ b2,
    const float* __restrict__ W3, const float* __restrict__ b3,
    float* __restrict__ F)
{
    __shared__ uint   sX[256];       // packed-f16 (x0,x1) per GP-row
    __shared__ float2 sG[256];       // (p,q) per GP-row, pre-normalized
    __shared__ float  sB[256][17];   // P[8],Q[8] per GP, pad -> conflict-free

    const int tid  = threadIdx.x;
    const int lane = tid & 63;
    const int wv   = tid >> 6;
    const int quad = lane >> 4;
    const int l15  = lane & 15;
    const int g    = tid & 3;            // gauss point of this thread
    const int e    = blockIdx.x * 64 + (tid >> 2);
    const bool valid = (e < NELEM);

    const float SQ23 = 0.816496580927726f;
    const float si0 = scales_inp[0], si1 = scales_inp[1];
    const float li0 = limits_inp[0], li1 = limits_inp[1];
    const float isg0 = 1.0f / scales_grad[0], isg1 = 1.0f / scales_grad[1];
    const float b30c = b3[0] - limits_grad[0];
    const float b31c = b3[1] - limits_grad[1];

    // ---- phase 1: strain invariants for this thread's GP -> P,Q to LDS ----
    int nd = 0;                         // this thread's node id
    uint xw = 0u;
    if (valid) {
        nd = conn[4 * e + g];           // coalesced scalar: node g of element e
        const float2 uu  = *(const float2*)(u + 2 * nd);
        const float2 wv2 = *(const float2*)(weight1 + 2 * nd);
        const float vx = wv2.x * uu.x, vy = wv2.y * uu.y;
        float ue[8];
        ue[0] = SWZF(vx, 0x1C); ue[1] = SWZF(vy, 0x1C);
        ue[2] = SWZF(vx, 0x3C); ue[3] = SWZF(vy, 0x3C);
        ue[4] = SWZF(vx, 0x5C); ue[5] = SWZF(vy, 0x5C);
        ue[6] = SWZF(vx, 0x7C); ue[7] = SWZF(vy, 0x7C);

        // this GP's 96B of B -> registers, consumed within phase 1
        float Bg[24];
        const float4* Bp = (const float4*)(B + (size_t)(e * 4 + g) * 24);
#pragma unroll
        for (int t2 = 0; t2 < 6; t2++) {
            const float4 v = Bp[t2];
            Bg[4 * t2 + 0] = v.x; Bg[4 * t2 + 1] = v.y;
            Bg[4 * t2 + 2] = v.z; Bg[4 * t2 + 3] = v.w;
        }
        float s0 = 0.f, s1 = 0.f, s2 = 0.f;
#pragma unroll
        for (int j = 0; j < 8; j++) {
            s0 = fmaf(Bg[j],      ue[j], s0);
            s1 = fmaf(Bg[8 + j],  ue[j], s1);
            s2 = fmaf(Bg[16 + j], ue[j], s2);
        }
        const float ev  = s0 + s1;
        const float ev3 = ev * (1.0f / 3.0f);
        const float d00 = s0 - ev3, d11 = s1 - ev3, d22 = -ev3, d01 = 0.5f * s2;
        const float det = sqrtf(d00 * d00 + d11 * d11 + d22 * d22 + 2.0f * d01 * d01);
        const float rd  = __builtin_amdgcn_rcpf(det);
        const float es  = det * SQ23;
        const float wgt = Jacc[4 * e + g] * gp_w[g];
        const float sc  = SQ23 * rd * wgt;
        const float c00 = sc * d00, c11 = sc * d11, c01 = sc * d01;
        // EP[j] = p*P[j] + q*Q[j]
#pragma unroll
        for (int j = 0; j < 8; j++) {
            sB[tid][j]     = wgt * (Bg[j] + Bg[8 + j]);
            sB[tid][8 + j] = fmaf(c00, Bg[j], fmaf(c11, Bg[8 + j], c01 * Bg[16 + j]));
        }
        xw = __builtin_bit_cast(uint, pk(fmaf(ev, si0, li0), fmaf(es, si1, li1)));
    }
    sX[tid] = xw;                       // invalid lanes write zeros
    __syncthreads();

    // ---- weight fragments (loaded AFTER phase 1: no overlap with Bg) ----
    // Layer1 (prescaled by LAM): lane's 16 k's are f*32 + quad*8 + j
    half2v w1p[16];
    float  b1v[16];
#pragma unroll
    for (int f = 0; f < 2; f++)
#pragma unroll
        for (int j = 0; j < 8; j++) {
            const int k = f * 32 + quad * 8 + j;
            w1p[f * 8 + j] = pk(LAM * W1[k], LAM * W1[HID + k]);
            b1v[f * 8 + j] = LAM * b1[k];
        }
    // Layer2 frags (prescaled): W2[k][n = t*16+l15], used as the A operand
    half8v bf[4][2];
#pragma unroll
    for (int t = 0; t < 4; t++)
#pragma unroll
        for (int f = 0; f < 2; f++) {
            union { half8v v; uint uu[4]; } tmp;
#pragma unroll
            for (int jj = 0; jj < 4; jj++) {
                const int k0 = f * 32 + quad * 8 + 2 * jj;
                const int n  = t * 16 + l15;
                tmp.uu[jj] = __builtin_bit_cast(uint,
                    pk(LAM * W2[k0 * HID + n], LAM * W2[(k0 + 1) * HID + n]));
            }
            bf[t][f] = tmp.v;
        }
    // Layer2 bias + layer3 weights per hidden n = t*16 + quad*4 + reg
    float b2s[16], w3a[16], w3b[16];
#pragma unroll
    for (int t = 0; t < 4; t++)
#pragma unroll
        for (int reg = 0; reg < 4; reg++) {
            const int n = t * 16 + quad * 4 + reg;
            b2s[4 * t + reg] = LAM * b2[n];
            w3a[4 * t + reg] = W3[2 * n];
            w3b[4 * t + reg] = W3[2 * n + 1];
        }

    // ---- phase 2: swapped-MFMA MLP over this wave's 64 GP-rows ----
#pragma unroll 1
    for (int rt = 0; rt < 4; rt++) {
        const int tb = wv * 64 + rt * 16;
        const half2v xp = __builtin_bit_cast(half2v, sX[tb + l15]);

        // layer 1 -> h1 fragments (row m = l15, k per lane) used as B operand
        union { half8v v; uint uu[4]; } B0, B1;
#pragma unroll
        for (int jj = 0; jj < 4; jj++) {
            const float t0 = tanh2(fdot2(xp, w1p[2 * jj],     b1v[2 * jj]));
            const float t1 = tanh2(fdot2(xp, w1p[2 * jj + 1], b1v[2 * jj + 1]));
            const float t2 = tanh2(fdot2(xp, w1p[8 + 2 * jj],     b1v[8 + 2 * jj]));
            const float t3 = tanh2(fdot2(xp, w1p[8 + 2 * jj + 1], b1v[8 + 2 * jj + 1]));
            B0.uu[jj] = __builtin_bit_cast(uint, pk(t0, t1));
            B1.uu[jj] = __builtin_bit_cast(uint, pk(t2, t3));
        }

        // layer 2: D = (LAM W2^T) @ H1^T -> col j=l15 is GP-row, row = hidden
        float s0 = 0.f, s1 = 0.f;
#pragma unroll
        for (int t = 0; t < 4; t++) {
            float4v c = {b2s[4 * t + 0], b2s[4 * t + 1], b2s[4 * t + 2], b2s[4 * t + 3]};
            c = __builtin_amdgcn_mfma_f32_16x16x32_f16(bf[t][0], B0.v, c, 0, 0, 0);
            c = __builtin_amdgcn_mfma_f32_16x16x32_f16(bf[t][1], B1.v, c, 0, 0, 0);
#pragma unroll
            for (int reg = 0; reg < 4; reg++) {
                const float h = tanh2(c[reg]);
                s0 = fmaf(h, w3a[4 * t + reg], s0);
                s1 = fmaf(h, w3b[4 * t + reg], s1);
            }
        }
        // reduce over the 4 quads (hidden axis): lane^16 then lane^32
        s0 += SWZF(s0, 0x401F);
        s1 += SWZF(s1, 0x401F);
        s0 += __shfl_xor(s0, 32, 64);
        s1 += __shfl_xor(s1, 32, 64);
        // quad 0 writes pre-normalized (p,q) for row tb+l15
        if (quad == 0) {
            const float p = (s0 + b30c) * isg0;
            const float q = (s1 + b31c) * isg1;
            sG[tb + l15] = make_float2(p, q);
        }
    }
    __syncthreads();

    // ---- phase 3: EP[j] = sum_g p_g*P_g[j] + q_g*Q_g[j], 2 atomics ----
    if (valid) {
        const int ebase = tid & ~3;     // first GP-row of this element
        const int j0 = 2 * g;           // this thread's dof pair of EP[8]
        float a = 0.f, b = 0.f;
#pragma unroll
        for (int gp = 0; gp < 4; gp++) {
            const float2 pq = sG[ebase + gp];
            a = fmaf(pq.x, sB[ebase + gp][j0],
                fmaf(pq.y, sB[ebase + gp][8 + j0], a));
            b = fmaf(pq.x, sB[ebase + gp][j0 + 1],
                fmaf(pq.y, sB[ebase + gp][9 + j0], b));
        }
        atomicAdd(&F[2 * nd],     a);
        atomicAdd(&F[2 * nd + 1], b);
    }
}

extern "C" void kernel_launch(void* const* d_in, const int* in_sizes, int n_in,
                              void* d_out, int out_size, void* d_ws, size_t ws_size,
                              hipStream_t stream) {
    const float* u           = (const float*)d_in[0];
    const float* B           = (const float*)d_in[1];
    const float* Jacc        = (const float*)d_in[2];
    const float* gp_w        = (const float*)d_in[3];
    const int*   conn        = (const int*)  d_in[4];
    const float* weight1     = (const float*)d_in[5];
    const float* scales_inp  = (const float*)d_in[6];
    const float* limits_inp  = (const float*)d_in[7];
    const float* scales_grad = (const float*)d_in[8];
    const float* limits_grad = (const float*)d_in[9];
    const float* W1          = (const float*)d_in[10];
    const float* b1          = (const float*)d_in[11];
    const float* W2          = (const float*)d_in[12];
    const float* b2          = (const float*)d_in[13];
    const float* W3          = (const float*)d_in[14];
    const float* b3          = (const float*)d_in[15];
    float* F = (float*)d_out;

    (void)hipMemsetAsync(d_out, 0, sizeof(float) * NDOF, stream);

    const int grid = (NELEM + 63) / 64;   // 64 elements (256 GPs) per block
    fem_force_kernel<<<grid, 256, 0, stream>>>(
        u, B, Jacc, gp_w, conn, weight1, scales_inp, limits_inp,
        scales_grad, limits_grad, W1, b1, W2, b2, W3, b3, F);
}